// Round 14
// baseline (98.687 us; speedup 1.0000x reference)
//
#include <hip/hip_runtime.h>
#include <hip/hip_bf16.h>

// Round 14: TLP experiment. r9-r13 all plateau at 41-49us with no pipe >50%
// busy and ~8 waves/CU resident (LDS ~18KB per row is the binding resource in
// every variant). This round keeps r13's arithmetic EXACTLY but shares one
// row between 2 waves (128-thread block): LDS/block 19.4KB -> 8 blocks/CU =
// 16 waves/CU (2x r13). Wave0: tiles 0-12, nt 0-1; wave1: tiles 13-24,
// nt 2-3. Three 2-wave barriers. If flat, TLP is not the limiter.

#define NF 40
#define ED 64
#define AS 32
#define NTILE 25
#define NSLOT 800
#define XS_STRIDE 68   // floats; 272B rows, 16B-aligned
#define SM_STRIDE 72   // shorts; 144B rows, 16B-aligned

typedef __attribute__((ext_vector_type(4))) float f32x4;
typedef __attribute__((ext_vector_type(16))) float f32x16;
typedef __attribute__((ext_vector_type(8))) short bf16x8;

union ABFrag { bf16x8 v; unsigned int u[4]; uint4 q; };

// bf16 round-half-up: bits(f)+0x8000 >> 16. == RNE except on exact ties.
__device__ __forceinline__ unsigned short bfbits_rn(float f) {
  return (unsigned short)((__float_as_uint(f) + 0x8000u) >> 16);
}
// pack2: (bf16(a)) | (bf16(b) << 16) in 3 VALU (2 adds + v_perm byte-pack).
__device__ __forceinline__ unsigned int pack2(float a, float b) {
  unsigned int ua = __float_as_uint(a) + 0x8000u;
  unsigned int ub = __float_as_uint(b) + 0x8000u;
  return __builtin_amdgcn_perm(ub, ua, 0x07060302u);
}
// split: hi = pack2(a,b); lo = pack2 of the exact residuals.
__device__ __forceinline__ void split_pack(float a, float b,
                                           unsigned int& hi, unsigned int& lo) {
  hi = pack2(a, b);
  float ra = a - __uint_as_float(hi << 16);
  float rb = b - __uint_as_float(hi & 0xffff0000u);
  lo = pack2(ra, rb);
}

__global__ __launch_bounds__(128) void afm_kernel(
    const float* __restrict__ x, const float* __restrict__ attn_w,
    const float* __restrict__ attn_b, const float* __restrict__ proj_w,
    const float* __restrict__ proj_b, const float* __restrict__ fc_w,
    const float* __restrict__ fc_b, float* __restrict__ out) {
  __shared__ __align__(16) float xs[NF * XS_STRIDE];            // 10880 B
  __shared__ __align__(16) unsigned short Smh[48 * SM_STRIDE];  // 6912 B
  __shared__ unsigned char pi_t[NSLOT], pj_t[NSLOT];            // 1600 B
  __shared__ float lsums[2], wsum[2];

  const int tid = threadIdx.x;
  const int lane = tid & 63;
  const int w = tid >> 6;            // wave id (0/1)
  const int quad = lane >> 4;
  const int col = lane & 15;
  const int half = lane >> 5;        // 32x32 MFMA k-half
  const int m32 = lane & 31;         // 32x32 MFMA row/col index
  const int row = blockIdx.x;
  const float* xg = x + row * (NF * ED);

  // ---- P1: stage x row (640 float4 over 128 threads), zero Smh, tables.
#pragma unroll
  for (int v = 0; v < 5; ++v) {
    int e4 = v * 128 + tid;
    int f = e4 >> 4, c4 = e4 & 15;
    *(float4*)(xs + f * XS_STRIDE + c4 * 4) = *(const float4*)(xg + e4 * 4);
  }
#pragma unroll
  for (int v = 0; v < 14; ++v) {     // 1728 u32
    int e = v * 128 + tid;
    if (e < (48 * SM_STRIDE) / 2) ((unsigned int*)Smh)[e] = 0u;
  }
  // Tiles 0..19: 4i x 8j rectangles fully above the diagonal
  //   (j0=1:ib 0-1, j0=2:ib 0-3, j0=3:ib 0-5, j0=4:ib 0-7).
  // Tiles 20..24: diagonal 8-chunks [8k,8k+8): 28 in-chunk pairs + 4 pads.
  for (int s = tid; s < NSLOT; s += 128) {
    int t = s >> 5, m = s & 31;
    int i = 0, j = 255;  // default: pad
    if (t < 20) {
      int j0, ib;
      if (t < 2) { j0 = 1; ib = t; }
      else if (t < 6) { j0 = 2; ib = t - 2; }
      else if (t < 12) { j0 = 3; ib = t - 6; }
      else { j0 = 4; ib = t - 12; }
      i = ib * 4 + (m >> 3);
      j = j0 * 8 + (m & 7);
    } else if (m < 28) {
      int k = t - 20;
      int mm = m, a = 0;
      while (mm >= 7 - a) { mm -= 7 - a; ++a; }  // triu of 8
      i = 8 * k + a;
      j = 8 * k + a + 1 + mm;
    }
    pi_t[s] = (unsigned char)i;
    pj_t[s] = (unsigned char)j;
  }

  // ---- per-lane constants (identical in both waves).
  // A-frag (32x32x16): A[mrow=m32][k=half*8+e]; A = W^T -> w[d][a=m32].
  ABFrag fwh[4], fwl[4];
#pragma unroll
  for (int s4 = 0; s4 < 4; ++s4)
#pragma unroll
    for (int p = 0; p < 4; ++p) {
      int d = s4 * 16 + half * 8 + 2 * p;
      split_pack(attn_w[d * AS + m32], attn_w[(d + 1) * AS + m32],
                 fwh[s4].u[p], fwl[s4].u[p]);
    }
  // Epilogue constants: C/D row(reg) = (reg&3) + 8*(reg>>2) + 4*half.
  float abv[16], pwv[16];
#pragma unroll
  for (int r = 0; r < 16; ++r) {
    int arow = (r & 3) + 8 * (r >> 2) + 4 * half;
    abv[r] = attn_b[arow];
    pwv[r] = proj_w[arow];
  }
  const float fcb = fc_b[0];
  __syncthreads();  // B1: xs/Smh-zero/tables ready

  // ---- P2: wave w owns tiles [t0,t1). 32x32x16 MFMA (pairs on N) with
  // fused exp + bf16 scatter + denominator partial. No max-subtract.
  const int t0 = w ? 13 : 0;
  const int t1 = w ? NTILE : 13;
  float lsum = 0.f;
  for (int t = t0; t < t1; ++t) {
    const int slot = t * 32 + m32;
    const int fi = pi_t[slot];
    const int fjr = pj_t[slot];
    const bool pad = (fjr == 255);
    const int fj = pad ? 0 : fjr;
    const float* xi = xs + fi * XS_STRIDE + half * 8;
    const float* xj = xs + fj * XS_STRIDE + half * 8;
    f32x16 acc0, acc1;
#pragma unroll
    for (int r = 0; r < 16; ++r) { acc0[r] = abv[r]; acc1[r] = 0.f; }
#pragma unroll
    for (int s4 = 0; s4 < 4; ++s4) {
      float4 i0 = *(const float4*)(xi + s4 * 16);
      float4 i1 = *(const float4*)(xi + s4 * 16 + 4);
      float4 j0 = *(const float4*)(xj + s4 * 16);
      float4 j1 = *(const float4*)(xj + s4 * 16 + 4);
      ABFrag ip;  // B-frag: B[k=half*8+e][n=m32] = ip[pair][d]
      ip.u[0] = pack2(i0.x * j0.x, i0.y * j0.y);
      ip.u[1] = pack2(i0.z * j0.z, i0.w * j0.w);
      ip.u[2] = pack2(i1.x * j1.x, i1.y * j1.y);
      ip.u[3] = pack2(i1.z * j1.z, i1.w * j1.w);
      if (s4 & 1) {  // two accumulator chains
        acc1 = __builtin_amdgcn_mfma_f32_32x32x16_bf16(fwh[s4].v, ip.v, acc1, 0, 0, 0);
        acc1 = __builtin_amdgcn_mfma_f32_32x32x16_bf16(fwl[s4].v, ip.v, acc1, 0, 0, 0);
      } else {
        acc0 = __builtin_amdgcn_mfma_f32_32x32x16_bf16(fwh[s4].v, ip.v, acc0, 0, 0, 0);
        acc0 = __builtin_amdgcn_mfma_f32_32x32x16_bf16(fwl[s4].v, ip.v, acc0, 0, 0, 0);
      }
    }
    float lg = 0.f;  // fused relu+proj (bias pre-folded into acc0)
#pragma unroll
    for (int r = 0; r < 16; ++r)
      lg = fmaf(fmaxf(acc0[r] + acc1[r], 0.f), pwv[r], lg);
    lg += __shfl_xor(lg, 32);
    if ((lane < 32) & !pad) {
      float e = __expf(lg);
      Smh[fi * SM_STRIDE + fjr] = bfbits_rn(e);
      lsum += e;
    }
  }
#pragma unroll
  for (int off = 1; off <= 32; off <<= 1) lsum += __shfl_xor(lsum, off);
  if (lane == 0) lsums[w] = lsum;
  __syncthreads();  // B2: full Smh + both lsums ready
  const float total = lsums[0] + lsums[1];

  // ---- P4: M = S_up @ X via 16x16x32 MFMA; wave w owns nt = 2w, 2w+1.
  // attn[d] = sum_i x_i[d]*M[i][d] = sum_{i<j} e_ij x_i[d] x_j[d].
  ABFrag fsh[3][2];
#pragma unroll
  for (int kt = 0; kt < 2; ++kt) {
    const int kbase = kt * 32 + quad * 8;
#pragma unroll
    for (int it = 0; it < 3; ++it)
      fsh[it][kt].q = *(const uint4*)(Smh + (it * 16 + col) * SM_STRIDE + kbase);
  }
  float ypart = 0.f;
#pragma unroll
  for (int ntl = 0; ntl < 2; ++ntl) {
    const int dcol = (w * 2 + ntl) * 16 + col;
    ABFrag fxh[2], fxl[2];
#pragma unroll
    for (int kt = 0; kt < 2; ++kt) {
      const int kbase = kt * 32 + quad * 8;
      if ((kt == 0) | (quad == 0)) {  // k < 40
#pragma unroll
        for (int p = 0; p < 4; ++p) {
          float v0 = xs[(kbase + 2 * p) * XS_STRIDE + dcol];
          float v1 = xs[(kbase + 2 * p + 1) * XS_STRIDE + dcol];
          split_pack(v0, v1, fxh[kt].u[p], fxl[kt].u[p]);
        }
      } else {
        fxh[kt].q = make_uint4(0, 0, 0, 0);
        fxl[kt].q = make_uint4(0, 0, 0, 0);
      }
    }
    f32x4 mac[3];
#pragma unroll
    for (int it = 0; it < 3; ++it) {
      f32x4 z = {0.f, 0.f, 0.f, 0.f};
      z = __builtin_amdgcn_mfma_f32_16x16x32_bf16(fsh[it][0].v, fxh[0].v, z, 0, 0, 0);
      z = __builtin_amdgcn_mfma_f32_16x16x32_bf16(fsh[it][1].v, fxh[1].v, z, 0, 0, 0);
      z = __builtin_amdgcn_mfma_f32_16x16x32_bf16(fsh[it][0].v, fxl[0].v, z, 0, 0, 0);
      z = __builtin_amdgcn_mfma_f32_16x16x32_bf16(fsh[it][1].v, fxl[1].v, z, 0, 0, 0);
      mac[it] = z;
    }
    float part = 0.f;
#pragma unroll
    for (int r = 0; r < 4; ++r)
      part = fmaf(mac[0][r], xs[(quad * 4 + r) * XS_STRIDE + dcol], part);
#pragma unroll
    for (int r = 0; r < 4; ++r)
      part = fmaf(mac[1][r], xs[(16 + quad * 4 + r) * XS_STRIDE + dcol], part);
    if (quad < 2) {
#pragma unroll
      for (int r = 0; r < 4; ++r)
        part = fmaf(mac[2][r], xs[(32 + quad * 4 + r) * XS_STRIDE + dcol], part);
    }
    part += __shfl_xor(part, 16);  // reduce over quads (i groups)
    part += __shfl_xor(part, 32);
    ypart = fmaf(part, fc_w[dcol], ypart);
  }
#pragma unroll
  for (int off = 1; off <= 8; off <<= 1) ypart += __shfl_xor(ypart, off);
  if (lane == 0) wsum[w] = ypart;
  __syncthreads();  // B3: both halves of y ready
  if (tid == 0) out[row] = (wsum[0] + wsum[1]) / total + fcb;
  (void)proj_b;  // cancels in softmax
}

extern "C" void kernel_launch(void* const* d_in, const int* in_sizes, int n_in,
                              void* d_out, int out_size, void* d_ws, size_t ws_size,
                              hipStream_t stream) {
  (void)in_sizes; (void)n_in; (void)out_size; (void)d_ws; (void)ws_size;
  afm_kernel<<<2048, 128, 0, stream>>>(
      (const float*)d_in[0], (const float*)d_in[1], (const float*)d_in[2],
      (const float*)d_in[3], (const float*)d_in[4], (const float*)d_in[5],
      (const float*)d_in[6], (float*)d_out);
}